// Round 5
// baseline (107.924 us; speedup 1.0000x reference)
//
#include <hip/hip_runtime.h>
#include <hip/hip_bf16.h>
#include <math.h>

constexpr int NQ   = 22500;      // 150*150
constexpr int NQP  = 22528;      // 352*64
constexpr int GH   = 150, GW = 150;

using f32x4 = __attribute__((ext_vector_type(4))) float;
using s16x8 = __attribute__((ext_vector_type(8))) short;

__device__ inline ushort f2bf(float f) {
    __hip_bfloat16 h = __float2bfloat16(f);
    return *reinterpret_cast<ushort*>(&h);
}
__device__ inline float bflo(uint u) { return __builtin_bit_cast(float, u << 16); }
__device__ inline float bfhi(uint u) { return __builtin_bit_cast(float, u & 0xffff0000u); }
__device__ inline float bf2f(uint u) { return __builtin_bit_cast(float, (u & 0xffffu) << 16); }

__device__ inline void gload_lds16(const void* g, void* l) {
    __builtin_amdgcn_global_load_lds(
        (const __attribute__((address_space(1))) void*)g,
        (__attribute__((address_space(3))) void*)l, 16, 0, 0);
}

// ---------------------------------------------------------------------------
// Front: per 64-row block, build qcat(bf16) = [query | query+query_pos] in
// LDS ONCE (XOR-swizzled, one barrier), then a BARRIER-FREE main loop:
// 7 N-tiles of Bcat(448x512, K-major); B fragments loaded straight from
// global (L2-resident, 16B/lane) into VGPRs; A fragments via ds_read_b128.
// Value tiles (nt<4) use K=256 only. 4 waves, 2x2 over a 64x64 tile.
// ---------------------------------------------------------------------------
__global__ __launch_bounds__(256, 2) void front_kernel(
    const float* __restrict__ query, const float* __restrict__ qpos,
    const ushort* __restrict__ Bcat,   // [448][512] bf16, K-major
    const float* __restrict__ bcat,    // [448]
    ushort* __restrict__ value_bf,     // NQ x 256
    ushort* __restrict__ offattn)      // NQ x 192
{
    __shared__ ushort Alds[64 * 512];  // 64 KB

    const int tid  = threadIdx.x;
    const int lane = tid & 63;
    const int w    = tid >> 6;
    const int wm   = w >> 1, wn = w & 1;
    const int l15  = lane & 15, l4 = lane >> 4;
    const int brow = blockIdx.x * 64;

    // ---- stage A: 64 rows x 512 cols qcat bf16, swizzled ----
    {
        const int row  = tid >> 2;
        const int cb   = (tid & 3) * 64;
        const int row_g = brow + row;
        const bool ok = row_g < NQ;
        const float4* qrow = (const float4*)(query + (size_t)row_g * 256 + cb);
        const float4* prow = (const float4*)(qpos  + (size_t)row_g * 256 + cb);
        const uint sw = (uint)(row & 7) << 4;
#pragma unroll
        for (int ci = 0; ci < 8; ++ci) {
            float4 qa = {}, qb = {}, pa = {}, pb = {};
            if (ok) { qa = qrow[ci*2]; qb = qrow[ci*2+1]; pa = prow[ci*2]; pb = prow[ci*2+1]; }
            s16x8 LW, RW;
            LW[0]=f2bf(qa.x); LW[1]=f2bf(qa.y); LW[2]=f2bf(qa.z); LW[3]=f2bf(qa.w);
            LW[4]=f2bf(qb.x); LW[5]=f2bf(qb.y); LW[6]=f2bf(qb.z); LW[7]=f2bf(qb.w);
            RW[0]=f2bf(qa.x+pa.x); RW[1]=f2bf(qa.y+pa.y); RW[2]=f2bf(qa.z+pa.z); RW[3]=f2bf(qa.w+pa.w);
            RW[4]=f2bf(qb.x+pb.x); RW[5]=f2bf(qb.y+pb.y); RW[6]=f2bf(qb.z+pb.z); RW[7]=f2bf(qb.w+pb.w);
            const int kL = cb + ci * 8, kR = 256 + kL;
            *(s16x8*)((char*)Alds + row * 1024 + (((uint)(kL * 2)) ^ sw)) = LW;
            *(s16x8*)((char*)Alds + row * 1024 + (((uint)(kR * 2)) ^ sw)) = RW;
        }
    }
    __syncthreads();

    const int rowA0 = wm * 32 + l15;
    const int rowA1 = rowA0 + 16;
    const char* aptr0 = (char*)Alds + rowA0 * 1024;
    const char* aptr1 = (char*)Alds + rowA1 * 1024;
    const uint asw0 = (uint)(rowA0 & 7) << 4;
    const uint asw1 = (uint)(rowA1 & 7) << 4;
    const uint kbase = (uint)(l4 * 8 * 2);      // byte offset of this lane's k-sub

    for (int nt = 0; nt < 7; ++nt) {
        const int ksteps = (nt < 4) ? 8 : 16;
        f32x4 acc[2][2] = {};
        const ushort* b0p = Bcat + (size_t)(nt * 64 + wn * 32 + l15) * 512 + l4 * 8;
        const ushort* b1p = b0p + 16 * 512;

#pragma unroll 4
        for (int ks = 0; ks < ksteps; ++ks) {
            const s16x8 b0 = *(const s16x8*)(b0p + ks * 32);
            const s16x8 b1 = *(const s16x8*)(b1p + ks * 32);
            const uint kb = kbase + (uint)(ks * 64);
            const s16x8 a0 = *(const s16x8*)(aptr0 + (kb ^ asw0));
            const s16x8 a1 = *(const s16x8*)(aptr1 + (kb ^ asw1));
            acc[0][0] = __builtin_amdgcn_mfma_f32_16x16x32_bf16(a0, b0, acc[0][0], 0, 0, 0);
            acc[1][0] = __builtin_amdgcn_mfma_f32_16x16x32_bf16(a1, b0, acc[1][0], 0, 0, 0);
            acc[0][1] = __builtin_amdgcn_mfma_f32_16x16x32_bf16(a0, b1, acc[0][1], 0, 0, 0);
            acc[1][1] = __builtin_amdgcn_mfma_f32_16x16x32_bf16(a1, b1, acc[1][1], 0, 0, 0);
        }

        // epilogue for tile nt (C/D: col=lane&15, row=(lane>>4)*4+r)
#pragma unroll
        for (int mi = 0; mi < 2; ++mi) {
#pragma unroll
            for (int r = 0; r < 4; ++r) {
                const int gr = brow + wm * 32 + mi * 16 + l4 * 4 + r;
                if (gr >= NQ) continue;
#pragma unroll
                for (int ni = 0; ni < 2; ++ni) {
                    const int gc = nt * 64 + wn * 32 + ni * 16 + l15;
                    const float v = acc[mi][ni][r] + bcat[gc];
                    if (gc < 256) value_bf[(size_t)gr * 256 + gc] = f2bf(v);
                    else          offattn[(size_t)gr * 192 + gc - 256] = f2bf(v);
                }
            }
        }
    }
}

// ---------------------------------------------------------------------------
// Weight prep: Bcat[448][512] = [W_v(zero-pad K>=256) | W_off | W_attn]^T,
// WoutT[256][256], bcat[448] = [b_v | b_off | b_attn]
// ---------------------------------------------------------------------------
__global__ __launch_bounds__(256) void prep_weights_kernel(
    const float* __restrict__ Wv, const float* __restrict__ Woff,
    const float* __restrict__ Wattn, const float* __restrict__ Wout,
    const float* __restrict__ bv, const float* __restrict__ boff,
    const float* __restrict__ battn,
    ushort* __restrict__ Bcat, ushort* __restrict__ WoutT, float* __restrict__ bcat)
{
    int t = blockIdx.x * 256 + threadIdx.x;
    if (t < 448 * 512) {
        const int col = t >> 9, k = t & 511;
        float v;
        if (col < 256)      v = (k < 256) ? Wv[k * 256 + col] : 0.f;
        else if (col < 384) v = Woff[k * 128 + (col - 256)];
        else                v = Wattn[k * 64 + (col - 384)];
        Bcat[t] = f2bf(v);
        return;
    }
    t -= 448 * 512;
    if (t < 65536) { const int n = t >> 8, k = t & 255; WoutT[t] = f2bf(Wout[k * 256 + n]); return; }
    t -= 65536;
    if (t < 448) bcat[t] = t < 256 ? bv[t] : (t < 384 ? boff[t - 256] : battn[t - 384]);
}

// ---------------------------------------------------------------------------
// Fused prep + gather. Block = 4 waves = 4 queries (XCD-swizzled).
// ---------------------------------------------------------------------------
__global__ __launch_bounds__(256) void msda_fused_kernel(
    const ushort* __restrict__ value_bf,   // NQ x 256
    const ushort* __restrict__ offattn,    // NQ x 192
    const float* __restrict__ refpts,      // (2, NQ, 1, 2)
    ushort* __restrict__ msda_bf)          // NQ x 256
{
    __shared__ uint4 Plds[4 * 64];

    constexpr int NB = NQ / 4;         // 5625
    constexpr int NX = 8;
    constexpr int qd = NB / NX, rr = NB % NX;
    const int bid = blockIdx.x;
    const int xcd = bid % NX, loc = bid / NX;
    const int swz = (xcd < rr ? xcd * (qd + 1) : rr * (qd + 1) + (xcd - rr) * qd) + loc;

    const int wv   = threadIdx.x >> 6;
    const int lane = threadIdx.x & 63;
    const int q    = swz * 4 + wv;

    // ---- prep: one point per lane ----
    {
        const int jj = (lane >> 2) & 1;
        const float lg = bf2f(offattn[(size_t)q * 192 + 128 + lane]);
        float mx = fmaxf(lg, __shfl_xor(lg, 1));
        mx = fmaxf(mx, __shfl_xor(mx, 2));
        const float e = expf(lg - mx);
        float s = e + __shfl_xor(e, 1);
        s = s + __shfl_xor(s, 2);
        const float aw = e * (0.5f / s);

        const uint opk = *(const uint*)(offattn + (size_t)q * 192 + lane * 2);
        const float2 rp = *(const float2*)(refpts + ((size_t)jj * NQ + q) * 2);
        const float x = rp.x * 150.f - 0.5f + bflo(opk);
        const float y = rp.y * 150.f - 0.5f + bfhi(opk);
        const float x0f = floorf(x), y0f = floorf(y);
        const float wx = x - x0f, wy = y - y0f;
        const int x0 = (int)x0f, y0 = (int)y0f;
        const float vx0 = (x0 >= 0 && x0 < GW) ? 1.f : 0.f;
        const float vx1 = (x0 >= -1 && x0 < GW - 1) ? 1.f : 0.f;
        const float vy0 = (y0 >= 0 && y0 < GH) ? 1.f : 0.f;
        const float vy1 = (y0 >= -1 && y0 < GH - 1) ? 1.f : 0.f;
        const int ix0 = min(max(x0, 0), GW - 1), ix1 = min(max(x0 + 1, 0), GW - 1);
        const int iy0 = min(max(y0, 0), GH - 1), iy1 = min(max(y0 + 1, 0), GH - 1);
        const float w00 = (1.f - wx) * (1.f - wy) * aw * vx0 * vy0;
        const float w01 = wx * (1.f - wy) * aw * vx1 * vy0;
        const float w10 = (1.f - wx) * wy * aw * vx0 * vy1;
        const float w11 = wx * wy * aw * vx1 * vy1;
        uint4 P;
        P.x = (uint)(iy0 * GW + ix0) | ((uint)(iy0 * GW + ix1) << 16);
        P.y = (uint)(iy1 * GW + ix0) | ((uint)(iy1 * GW + ix1) << 16);
        P.z = (uint)f2bf(w00) | ((uint)f2bf(w01) << 16);
        P.w = (uint)f2bf(w10) | ((uint)f2bf(w11) << 16);
        Plds[wv * 64 + lane] = P;
    }
    __syncthreads();

    // ---- gather: lane = h*8+cl owns 4 channels ----
    const int h  = lane >> 3;
    const int cl = lane & 7;
    const int c0 = h * 32 + cl * 4;
    const uint cb = (uint)c0 * 2;
    const uint4* pp = &Plds[wv * 64 + h * 8];
    const char* vbase = (const char*)value_bf;

    float a0 = 0.f, a1 = 0.f, a2 = 0.f, a3 = 0.f;
#pragma unroll
    for (int pt = 0; pt < 8; ++pt) {
        const uint4 P = pp[pt];
#pragma unroll
        for (int cr = 0; cr < 4; ++cr) {
            const uint idxw = (cr < 2) ? P.x : P.y;
            const uint wpk  = (cr < 2) ? P.z : P.w;
            const uint pix  = (cr & 1) ? (idxw >> 16) : (idxw & 0xffffu);
            const float wgt = (cr & 1) ? bfhi(wpk) : bflo(wpk);
            const uint2 v = *(const uint2*)(vbase + ((size_t)(pix << 9) + cb));
            a0 = fmaf(wgt, bflo(v.x), a0);
            a1 = fmaf(wgt, bfhi(v.x), a1);
            a2 = fmaf(wgt, bflo(v.y), a2);
            a3 = fmaf(wgt, bfhi(v.y), a3);
        }
    }
    ushort4 o;
    o.x = f2bf(a0); o.y = f2bf(a1); o.z = f2bf(a2); o.w = f2bf(a3);
    *(ushort4*)&msda_bf[(size_t)q * 256 + c0] = o;
}

// ---------------------------------------------------------------------------
// Output projection: out = msda @ WoutT^T + b_out + query  (f32 out)
// ---------------------------------------------------------------------------
__global__ __launch_bounds__(256) void gemm_out_kernel(
    const ushort* __restrict__ A, const ushort* __restrict__ Bt,
    const float* __restrict__ bias, const float* __restrict__ ident,
    float* __restrict__ C, int M)
{
    constexpr int BK = 32;
    __shared__ ushort As[128 * BK];
    __shared__ ushort Bs[64 * BK];

    const int tid  = threadIdx.x;
    const int lane = tid & 63;
    const int w    = tid >> 6;
    const int wm   = w >> 1, wn = w & 1;
    const int l15  = lane & 15, l4 = lane >> 4;
    const int brow = blockIdx.x * 128;
    const int bcol = blockIdx.y * 64;

    f32x4 acc[4][2] = {};

    for (int k0 = 0; k0 < 256; k0 += BK) {
#pragma unroll
        for (int c = 0; c < 2; ++c) {
            const int idx = c * 256 + tid;
            const ushort* src = A + (size_t)(brow + (idx >> 2)) * 256 + k0 + (idx & 3) * 8;
            gload_lds16(src, (char*)As + (c * 256 + w * 64) * 16);
        }
        {
            const int idx = tid;
            const ushort* src = Bt + (size_t)(bcol + (idx >> 2)) * 256 + k0 + (idx & 3) * 8;
            gload_lds16(src, (char*)Bs + (w * 64) * 16);
        }
        __syncthreads();

        s16x8 a[4], b[2];
#pragma unroll
        for (int mi = 0; mi < 4; ++mi)
            a[mi] = *(const s16x8*)&As[(wm * 64 + mi * 16 + l15) * BK + l4 * 8];
#pragma unroll
        for (int ni = 0; ni < 2; ++ni)
            b[ni] = *(const s16x8*)&Bs[(wn * 32 + ni * 16 + l15) * BK + l4 * 8];
#pragma unroll
        for (int mi = 0; mi < 4; ++mi)
#pragma unroll
            for (int ni = 0; ni < 2; ++ni)
                acc[mi][ni] = __builtin_amdgcn_mfma_f32_16x16x32_bf16(
                    a[mi], b[ni], acc[mi][ni], 0, 0, 0);
        __syncthreads();
    }

#pragma unroll
    for (int mi = 0; mi < 4; ++mi) {
#pragma unroll
        for (int r = 0; r < 4; ++r) {
            const int gr = brow + wm * 64 + mi * 16 + l4 * 4 + r;
            if (gr >= M) continue;
#pragma unroll
            for (int ni = 0; ni < 2; ++ni) {
                const int gc = bcol + wn * 32 + ni * 16 + l15;
                C[(size_t)gr * 256 + gc] = acc[mi][ni][r] + bias[gc] + ident[(size_t)gr * 256 + gc];
            }
        }
    }
}

// ---------------------------------------------------------------------------
extern "C" void kernel_launch(void* const* d_in, const int* in_sizes, int n_in,
                              void* d_out, int out_size, void* d_ws, size_t ws_size,
                              hipStream_t stream)
{
    const float* query     = (const float*)d_in[0];
    const float* query_pos = (const float*)d_in[1];
    const float* refpts    = (const float*)d_in[2];
    const float* W_off     = (const float*)d_in[3];
    const float* b_off     = (const float*)d_in[4];
    const float* W_attn    = (const float*)d_in[5];
    const float* b_attn    = (const float*)d_in[6];
    const float* W_v       = (const float*)d_in[7];
    const float* b_v       = (const float*)d_in[8];
    const float* W_out     = (const float*)d_in[9];
    const float* b_out     = (const float*)d_in[10];
    float* out             = (float*)d_out;

    char* base = (char*)d_ws;
    size_t o = 0;
    ushort* value_bf = (ushort*)(base + o); o += (size_t)NQP * 256 * 2;
    ushort* offattn  = (ushort*)(base + o); o += (size_t)NQP * 192 * 2;
    ushort* msda_bf  = (ushort*)(base + o); o += (size_t)NQP * 256 * 2;
    ushort* Bcat     = (ushort*)(base + o); o += 448 * 512 * 2;
    ushort* WoutT    = (ushort*)(base + o); o += 256 * 256 * 2;
    float*  bcat     = (float*)(base + o);  o += 448 * 4;

    prep_weights_kernel<<<(448 * 512 + 65536 + 448 + 255) / 256, 256, 0, stream>>>(
        W_v, W_off, W_attn, W_out, b_v, b_off, b_attn, Bcat, WoutT, bcat);

    front_kernel<<<NQP / 64, 256, 0, stream>>>(
        query, query_pos, Bcat, bcat, value_bf, offattn);

    msda_fused_kernel<<<NQ / 4, 256, 0, stream>>>(value_bf, offattn, refpts, msda_bf);

    gemm_out_kernel<<<dim3(NQP / 128, 4), 256, 0, stream>>>(
        msda_bf, WoutT, b_out, query, out, NQ);
}